// Round 1
// baseline (1127.071 us; speedup 1.0000x reference)
//
#include <hip/hip_runtime.h>

// EmbedLayerUpdate: 2 layers of  pre = W @ mu + b  (per batch, [Dout,K]x[K,64])
// followed by per-row relu-block MLP, fused into the GEMM epilogue.
// B=16, D0=2048, D1=D2=4096, P=64. All fp32 (baseline round).

#define BM 64
#define BK 64
#define LDSP 68   // padded leading dim (floats); 68*4=272 B keeps 16B alignment

__device__ __forceinline__ float dot4(const float4 a, const float4 b) {
    return a.x * b.x + a.y * b.y + a.z * b.z + a.w * b.w;
}

template <int K>
__global__ __launch_bounds__(256, 3)
void layer_kernel(const float* __restrict__ W,     // [Dout, K]
                  const float* __restrict__ bias,  // [Dout]
                  const float* __restrict__ mu_in, // [B, K, 64]
                  const float* __restrict__ lb, const float* __restrict__ ub,
                  const float* __restrict__ ps, const float* __restrict__ ss,
                  const float* __restrict__ mask,
                  const float* __restrict__ fc1W, const float* __restrict__ fc1b,
                  const float* __restrict__ fc11W, const float* __restrict__ fc11b,
                  const float* __restrict__ fc2W, const float* __restrict__ fc2b,
                  const float* __restrict__ fc21W, const float* __restrict__ fc21b,
                  float* __restrict__ out, const int Dout)
{
    __shared__ float sA[BK * LDSP];  // GEMM: Wt[k][r]   | epi: T[r][j], then U[r][j]
    __shared__ float sB[BK * LDSP];  // GEMM: mu[k][p]   | epi: H[r][j]
    __shared__ float sC[BM * LDSP];  //                    epi: Pre[r][p]

    const int tid = threadIdx.x;
    const int tx = tid & 15;          // 16 col-quads
    const int ty = tid >> 4;          // 16 row-quads
    const int b = blockIdx.y;
    const int orow0 = blockIdx.x * BM;

    const int lk = (tid & 15) * 4;    // loader: k offset (also p offset)
    const int lr = tid >> 4;          // loader: row base

    float acc[4][4] = {};

    // ---------------- main GEMM: pre = W @ mu ----------------
    for (int k0 = 0; k0 < K; k0 += BK) {
        __syncthreads();
        #pragma unroll
        for (int pass = 0; pass < 4; ++pass) {
            const int r = lr + 16 * pass;
            const float4 w4 = *(const float4*)&W[(orow0 + r) * K + k0 + lk];
            sA[(lk + 0) * LDSP + r] = w4.x;   // transpose into Wt[k][r]
            sA[(lk + 1) * LDSP + r] = w4.y;
            sA[(lk + 2) * LDSP + r] = w4.z;
            sA[(lk + 3) * LDSP + r] = w4.w;
            *(float4*)&sB[r * LDSP + lk] =
                *(const float4*)&mu_in[b * (K * 64) + (k0 + r) * 64 + lk];
        }
        __syncthreads();
        #pragma unroll 4
        for (int k = 0; k < BK; ++k) {
            const float4 av = *(const float4*)&sA[k * LDSP + ty * 4];
            const float4 bv = *(const float4*)&sB[k * LDSP + tx * 4];
            const float a4[4] = {av.x, av.y, av.z, av.w};
            const float b4[4] = {bv.x, bv.y, bv.z, bv.w};
            #pragma unroll
            for (int i = 0; i < 4; ++i)
                #pragma unroll
                for (int j = 0; j < 4; ++j)
                    acc[i][j] += a4[i] * b4[j];
        }
    }

    // ---------------- epilogue: relu block ----------------
    __syncthreads();   // all GEMM LDS reads done; buffers reusable

    // Pre[r][p] = acc + bias[row]  -> sC
    #pragma unroll
    for (int i = 0; i < 4; ++i) {
        const int r = ty * 4 + i;
        const float bs = bias[orow0 + r];
        float4 v;
        v.x = acc[i][0] + bs; v.y = acc[i][1] + bs;
        v.z = acc[i][2] + bs; v.w = acc[i][3] + bs;
        *(float4*)&sC[r * LDSP + tx * 4] = v;
    }

    // T[r][j] = relu(info @ fc1W^T + fc1b) -> sA
    #pragma unroll
    for (int i = 0; i < 4; ++i) {
        const int r = ty * 4 + i;
        const int g = b * Dout + orow0 + r;
        const float l = lb[g], u = ub[g];
        const float lt = fminf(l, 0.f), ut = fmaxf(u, 0.f);
        const float diff = ut - lt;
        const float ur = ut / (diff + 1e-8f);
        const float in0 = ur, in1 = 1.f - ur, in2 = diff, in3 = ps[g], in4 = ss[g];
        #pragma unroll
        for (int jj = 0; jj < 4; ++jj) {
            const int j = tx * 4 + jj;
            const float* w = fc1W + j * 5;
            const float v = fc1b[j] + in0 * w[0] + in1 * w[1] + in2 * w[2]
                          + in3 * w[3] + in4 * w[4];
            sA[r * LDSP + j] = fmaxf(v, 0.f);
        }
    }
    __syncthreads();

    // H[r][j] = T @ fc11W^T + fc11b -> sB
    {
        float h[4][4];
        #pragma unroll
        for (int jj = 0; jj < 4; ++jj) {
            const float bj = fc11b[tx * 4 + jj];
            #pragma unroll
            for (int i = 0; i < 4; ++i) h[i][jj] = bj;
        }
        #pragma unroll
        for (int kq = 0; kq < 16; ++kq) {
            float4 t4[4], w4[4];
            #pragma unroll
            for (int i = 0; i < 4; ++i)
                t4[i] = *(const float4*)&sA[(ty * 4 + i) * LDSP + kq * 4];
            #pragma unroll
            for (int jj = 0; jj < 4; ++jj)
                w4[jj] = *(const float4*)&fc11W[(tx * 4 + jj) * 64 + kq * 4];
            #pragma unroll
            for (int i = 0; i < 4; ++i)
                #pragma unroll
                for (int jj = 0; jj < 4; ++jj)
                    h[i][jj] += dot4(t4[i], w4[jj]);
        }
        #pragma unroll
        for (int i = 0; i < 4; ++i)
            #pragma unroll
            for (int jj = 0; jj < 4; ++jj)
                sB[(ty * 4 + i) * LDSP + tx * 4 + jj] = h[i][jj];
    }
    __syncthreads();

    // U[r][j] = relu([Pre|H] @ fc2W^T + fc2b) -> sA (T is dead now)
    {
        float uacc[4][4];
        #pragma unroll
        for (int jj = 0; jj < 4; ++jj) {
            const float bj = fc2b[tx * 4 + jj];
            #pragma unroll
            for (int i = 0; i < 4; ++i) uacc[i][jj] = bj;
        }
        #pragma unroll
        for (int kq = 0; kq < 16; ++kq) {
            float4 p4[4], h4[4], wp[4], wh[4];
            #pragma unroll
            for (int i = 0; i < 4; ++i) {
                p4[i] = *(const float4*)&sC[(ty * 4 + i) * LDSP + kq * 4];
                h4[i] = *(const float4*)&sB[(ty * 4 + i) * LDSP + kq * 4];
            }
            #pragma unroll
            for (int jj = 0; jj < 4; ++jj) {
                wp[jj] = *(const float4*)&fc2W[(tx * 4 + jj) * 128 + kq * 4];
                wh[jj] = *(const float4*)&fc2W[(tx * 4 + jj) * 128 + 64 + kq * 4];
            }
            #pragma unroll
            for (int i = 0; i < 4; ++i)
                #pragma unroll
                for (int jj = 0; jj < 4; ++jj)
                    uacc[i][jj] += dot4(p4[i], wp[jj]) + dot4(h4[i], wh[jj]);
        }
        #pragma unroll
        for (int i = 0; i < 4; ++i)
            #pragma unroll
            for (int jj = 0; jj < 4; ++jj)
                sA[(ty * 4 + i) * LDSP + tx * 4 + jj] = fmaxf(uacc[i][jj], 0.f);
    }
    __syncthreads();

    // Out[r][j] = (U @ fc21W^T + fc21b) * mask[row]
    {
        float o[4][4];
        #pragma unroll
        for (int jj = 0; jj < 4; ++jj) {
            const float bj = fc21b[tx * 4 + jj];
            #pragma unroll
            for (int i = 0; i < 4; ++i) o[i][jj] = bj;
        }
        #pragma unroll
        for (int kq = 0; kq < 16; ++kq) {
            float4 u4[4], w4[4];
            #pragma unroll
            for (int i = 0; i < 4; ++i)
                u4[i] = *(const float4*)&sA[(ty * 4 + i) * LDSP + kq * 4];
            #pragma unroll
            for (int jj = 0; jj < 4; ++jj)
                w4[jj] = *(const float4*)&fc21W[(tx * 4 + jj) * 64 + kq * 4];
            #pragma unroll
            for (int i = 0; i < 4; ++i)
                #pragma unroll
                for (int jj = 0; jj < 4; ++jj)
                    o[i][jj] += dot4(u4[i], w4[jj]);
        }
        #pragma unroll
        for (int i = 0; i < 4; ++i) {
            const int r = ty * 4 + i;
            const int g = b * Dout + orow0 + r;
            const float m = mask[g];
            float4 v;
            v.x = o[i][0] * m; v.y = o[i][1] * m;
            v.z = o[i][2] * m; v.w = o[i][3] * m;
            *(float4*)&out[g * 64 + tx * 4] = v;
        }
    }
}

extern "C" void kernel_launch(void* const* d_in, const int* in_sizes, int n_in,
                              void* d_out, int out_size, void* d_ws, size_t ws_size,
                              hipStream_t stream) {
    const float* mu0   = (const float*)d_in[0];
    const float* lb1   = (const float*)d_in[1];
    const float* ub1   = (const float*)d_in[2];
    const float* lb2   = (const float*)d_in[3];
    const float* ub2   = (const float*)d_in[4];
    const float* ps1   = (const float*)d_in[5];
    const float* ss1   = (const float*)d_in[6];
    const float* ps2   = (const float*)d_in[7];
    const float* ss2   = (const float*)d_in[8];
    const float* mask1 = (const float*)d_in[9];
    const float* mask2 = (const float*)d_in[10];
    const float* W1    = (const float*)d_in[11];
    const float* b1    = (const float*)d_in[12];
    const float* W2    = (const float*)d_in[13];
    const float* b2    = (const float*)d_in[14];
    const float* fc1W  = (const float*)d_in[15];
    const float* fc1b  = (const float*)d_in[16];
    const float* fc11W = (const float*)d_in[17];
    const float* fc11b = (const float*)d_in[18];
    const float* fc2W  = (const float*)d_in[19];
    const float* fc2b  = (const float*)d_in[20];
    const float* fc21W = (const float*)d_in[21];
    const float* fc21b = (const float*)d_in[22];

    float* mu1 = (float*)d_out;                       // [16*4096*64]
    float* mu2 = (float*)d_out + 16 * 4096 * 64;      // [16*4096*64]

    dim3 grid(4096 / BM, 16), blk(256);
    layer_kernel<2048><<<grid, blk, 0, stream>>>(
        W1, b1, mu0, lb1, ub1, ps1, ss1, mask1,
        fc1W, fc1b, fc11W, fc11b, fc2W, fc2b, fc21W, fc21b, mu1, 4096);
    layer_kernel<4096><<<grid, blk, 0, stream>>>(
        W2, b2, mu1, lb2, ub2, ps2, ss2, mask2,
        fc1W, fc1b, fc11W, fc11b, fc2W, fc2b, fc21W, fc21b, mu2, 4096);
}

// Round 2
// 199.415 us; speedup vs baseline: 5.6519x; 5.6519x over previous
//
#include <hip/hip_runtime.h>
#include <hip/hip_bf16.h>

// EmbedLayerUpdate on MFMA. B=16, D0=2048, D1=D2=4096, P=64.
// Per layer: pre = W @ mu + b  ([4096,K]x[K,64] per batch), then relu-block
// (fc1 VALU; fc11/fc2/fc21 as MFMA stages through swizzled LDS tiles).
// Block: 256 thr = 4 waves (2x2), BM=128 rows, BN=64 (=P), BK=64.

#define DOUT 4096

typedef __bf16 bf16x8 __attribute__((ext_vector_type(8)));
typedef float  f32x4  __attribute__((ext_vector_type(4)));

__device__ __forceinline__ __bf16 bfc(float x) { return (__bf16)x; }

// 128-byte rows (64 bf16), XOR-swizzle 16B chunks with row&7  (G4 fix)
__device__ __forceinline__ int aoff(int r, int c16) {
    return (r << 7) + ((c16 << 4) ^ ((r & 7) << 4));
}
// 256-byte rows (128 bf16), XOR-swizzle with row&15
__device__ __forceinline__ int eoff(int r, int byteoff) {
    return (r << 8) + (byteoff ^ ((r & 15) << 4));
}

template <int K>
__global__ __launch_bounds__(256, 2)
void layer_kernel(const float* __restrict__ W, const float* __restrict__ bias,
                  const float* __restrict__ mu_in,
                  const float* __restrict__ lb, const float* __restrict__ ub,
                  const float* __restrict__ ps, const float* __restrict__ ss,
                  const float* __restrict__ mask,
                  const float* __restrict__ fc1W, const float* __restrict__ fc1b,
                  const float* __restrict__ fc11W, const float* __restrict__ fc11b,
                  const float* __restrict__ fc2W, const float* __restrict__ fc2b,
                  const float* __restrict__ fc21W, const float* __restrict__ fc21b,
                  float* __restrict__ out)
{
    __shared__ __align__(16) char smA[128 * 128];   // A tile | T | U   (bf16)
    __shared__ __align__(16) char smB[64 * 128];    // Bt[p][k]         (bf16)
    __shared__ __align__(16) char smE[128 * 256];   // E = [pre | H]    (bf16)
    __shared__ float rowd[128];                      // b1[row]
    __shared__ float rowm[128];                      // mask[row]

    const int tid = threadIdx.x;
    const int b = blockIdx.x;                        // batch-major: 16 blocks share W panel
    const int orow0 = blockIdx.y * 128;
    const int lane = tid & 63;
    const int wv = tid >> 6;
    const int wm = wv >> 1, wn = wv & 1;             // 2x2 waves, wave tile 64x32
    const int lr = lane & 15, lg = lane >> 4;

    if (tid < 128) {
        rowd[tid] = bias[orow0 + tid];
        rowm[tid] = mask[b * DOUT + orow0 + tid];
    }

    const f32x4 z = {0.f, 0.f, 0.f, 0.f};
    f32x4 acc[4][2];
    #pragma unroll
    for (int m = 0; m < 4; ++m)
        #pragma unroll
        for (int n = 0; n < 2; ++n) acc[m][n] = z;

    // ---------------- main GEMM: pre = W @ mu ----------------
    for (int k0 = 0; k0 < K; k0 += 64) {
        __syncthreads();
        // A: W[orow0+row][k0+..] -> smA[row][k] bf16 (k-contiguous, swizzled)
        #pragma unroll
        for (int q = 0; q < 4; ++q) {
            const int row = (tid >> 3) + 32 * q;
            const int chk = tid & 7;                 // 8-elem chunk within 64 k
            const float4* gp = (const float4*)(W + (size_t)(orow0 + row) * K + k0 + chk * 8);
            const float4 x0 = gp[0], x1 = gp[1];
            bf16x8 v;
            v[0] = bfc(x0.x); v[1] = bfc(x0.y); v[2] = bfc(x0.z); v[3] = bfc(x0.w);
            v[4] = bfc(x1.x); v[5] = bfc(x1.y); v[6] = bfc(x1.z); v[7] = bfc(x1.w);
            *(bf16x8*)(smA + aoff(row, chk)) = v;
        }
        // B: mu[k0+k][p] -> smB[p][k] bf16 (transpose via b16 scatter)
        #pragma unroll
        for (int q = 0; q < 4; ++q) {
            const int k = 16 * q + (tid >> 4);
            const int p4 = (tid & 15) * 4;
            const float4 x = *(const float4*)(mu_in + (size_t)b * K * 64 + (size_t)(k0 + k) * 64 + p4);
            const float xv[4] = {x.x, x.y, x.z, x.w};
            #pragma unroll
            for (int i = 0; i < 4; ++i) {
                const int p = p4 + i;
                *(__bf16*)(smB + (p << 7) + ((2 * k) ^ ((p & 7) << 4))) = bfc(xv[i]);
            }
        }
        __syncthreads();
        #pragma unroll
        for (int ks = 0; ks < 2; ++ks) {
            bf16x8 a[4], bb[2];
            #pragma unroll
            for (int m = 0; m < 4; ++m)
                a[m] = *(const bf16x8*)(smA + aoff(wm * 64 + m * 16 + lr, ks * 4 + lg));
            #pragma unroll
            for (int n = 0; n < 2; ++n)
                bb[n] = *(const bf16x8*)(smB + aoff(wn * 32 + n * 16 + lr, ks * 4 + lg));
            #pragma unroll
            for (int m = 0; m < 4; ++m)
                #pragma unroll
                for (int n = 0; n < 2; ++n)
                    acc[m][n] = __builtin_amdgcn_mfma_f32_16x16x32_bf16(a[m], bb[n], acc[m][n], 0, 0, 0);
        }
    }
    __syncthreads();   // main-loop LDS reads done; smA/smB reusable

    // ---------------- epilogue phase 1: T = relu(info@fc1W^T+fc1b) -> smA;
    //                  pre + b1 -> smE cols 0..63 ----------------
    {
        const int row = tid >> 1;
        const int j0 = (tid & 1) * 32;
        const int g = b * DOUT + orow0 + row;
        const float lv = lb[g], uv = ub[g];
        const float lt = fminf(lv, 0.f), ut = fmaxf(uv, 0.f);
        const float diff = ut - lt;
        const float urr = ut / (diff + 1e-8f);
        const float lrr = 1.f - urr, i3 = ps[g], i4 = ss[g];
        #pragma unroll
        for (int c = 0; c < 4; ++c) {
            bf16x8 v;
            #pragma unroll
            for (int jj = 0; jj < 8; ++jj) {
                const int j = j0 + c * 8 + jj;
                const float* w = fc1W + j * 5;
                const float t = fc1b[j] + urr * w[0] + lrr * w[1] + diff * w[2]
                              + i3 * w[3] + i4 * w[4];
                v[jj] = bfc(fmaxf(t, 0.f));
            }
            *(bf16x8*)(smA + aoff(row, (j0 >> 3) + c)) = v;
        }
    }
    #pragma unroll
    for (int m = 0; m < 4; ++m)
        #pragma unroll
        for (int n = 0; n < 2; ++n) {
            const int col = wn * 32 + n * 16 + lr;
            #pragma unroll
            for (int r = 0; r < 4; ++r) {
                const int row = wm * 64 + m * 16 + lg * 4 + r;   // C-frag: col=lane&15, row=4*(lane>>4)+r
                *(__bf16*)(smE + eoff(row, 2 * col)) = bfc(acc[m][n][r] + rowd[row]);
            }
        }
    __syncthreads();

    // ---------------- H = T @ fc11W^T + fc11b -> smE cols 64..127 ----------------
    {
        f32x4 hacc[4][2];
        #pragma unroll
        for (int m = 0; m < 4; ++m)
            #pragma unroll
            for (int n = 0; n < 2; ++n) hacc[m][n] = z;
        #pragma unroll
        for (int ks = 0; ks < 2; ++ks) {
            bf16x8 a[4];
            #pragma unroll
            for (int m = 0; m < 4; ++m)
                a[m] = *(const bf16x8*)(smA + aoff(wm * 64 + m * 16 + lr, ks * 4 + lg));
            #pragma unroll
            for (int n = 0; n < 2; ++n) {
                const int j = wn * 32 + n * 16 + lr;
                const float4* wp = (const float4*)(fc11W + j * 64 + ks * 32 + lg * 8);
                const float4 w0 = wp[0], w1 = wp[1];
                bf16x8 bw;
                bw[0] = bfc(w0.x); bw[1] = bfc(w0.y); bw[2] = bfc(w0.z); bw[3] = bfc(w0.w);
                bw[4] = bfc(w1.x); bw[5] = bfc(w1.y); bw[6] = bfc(w1.z); bw[7] = bfc(w1.w);
                #pragma unroll
                for (int m = 0; m < 4; ++m)
                    hacc[m][n] = __builtin_amdgcn_mfma_f32_16x16x32_bf16(a[m], bw, hacc[m][n], 0, 0, 0);
            }
        }
        #pragma unroll
        for (int n = 0; n < 2; ++n) {
            const int j = wn * 32 + n * 16 + lr;
            const float bj = fc11b[j];
            #pragma unroll
            for (int m = 0; m < 4; ++m)
                #pragma unroll
                for (int r = 0; r < 4; ++r) {
                    const int row = wm * 64 + m * 16 + lg * 4 + r;
                    *(__bf16*)(smE + eoff(row, 2 * (64 + j))) = bfc(hacc[m][n][r] + bj);
                }
        }
    }
    __syncthreads();

    // ---------------- U = relu(E @ fc2W^T + fc2b) -> smA ----------------
    {
        f32x4 uacc[4][2];
        #pragma unroll
        for (int m = 0; m < 4; ++m)
            #pragma unroll
            for (int n = 0; n < 2; ++n) uacc[m][n] = z;
        #pragma unroll
        for (int ks = 0; ks < 4; ++ks) {             // K = 128
            bf16x8 a[4];
            #pragma unroll
            for (int m = 0; m < 4; ++m) {
                const int row = wm * 64 + m * 16 + lr;
                a[m] = *(const bf16x8*)(smE + eoff(row, ks * 64 + lg * 16));
            }
            #pragma unroll
            for (int n = 0; n < 2; ++n) {
                const int j = wn * 32 + n * 16 + lr;
                const float4* wp = (const float4*)(fc2W + j * 128 + ks * 32 + lg * 8);
                const float4 w0 = wp[0], w1 = wp[1];
                bf16x8 bw;
                bw[0] = bfc(w0.x); bw[1] = bfc(w0.y); bw[2] = bfc(w0.z); bw[3] = bfc(w0.w);
                bw[4] = bfc(w1.x); bw[5] = bfc(w1.y); bw[6] = bfc(w1.z); bw[7] = bfc(w1.w);
                #pragma unroll
                for (int m = 0; m < 4; ++m)
                    uacc[m][n] = __builtin_amdgcn_mfma_f32_16x16x32_bf16(a[m], bw, uacc[m][n], 0, 0, 0);
            }
        }
        #pragma unroll
        for (int n = 0; n < 2; ++n) {
            const int j = wn * 32 + n * 16 + lr;
            const float bj = fc2b[j];
            #pragma unroll
            for (int m = 0; m < 4; ++m)
                #pragma unroll
                for (int r = 0; r < 4; ++r) {
                    const int row = wm * 64 + m * 16 + lg * 4 + r;
                    *(__bf16*)(smA + (row << 7) + ((2 * j) ^ ((row & 7) << 4))) =
                        bfc(fmaxf(uacc[m][n][r] + bj, 0.f));
                }
        }
    }
    __syncthreads();

    // ---------------- out = (U @ fc21W^T + fc21b) * mask ----------------
    {
        f32x4 oacc[4][2];
        #pragma unroll
        for (int m = 0; m < 4; ++m)
            #pragma unroll
            for (int n = 0; n < 2; ++n) oacc[m][n] = z;
        #pragma unroll
        for (int ks = 0; ks < 2; ++ks) {
            bf16x8 a[4];
            #pragma unroll
            for (int m = 0; m < 4; ++m)
                a[m] = *(const bf16x8*)(smA + aoff(wm * 64 + m * 16 + lr, ks * 4 + lg));
            #pragma unroll
            for (int n = 0; n < 2; ++n) {
                const int j = wn * 32 + n * 16 + lr;
                const float4* wp = (const float4*)(fc21W + j * 64 + ks * 32 + lg * 8);
                const float4 w0 = wp[0], w1 = wp[1];
                bf16x8 bw;
                bw[0] = bfc(w0.x); bw[1] = bfc(w0.y); bw[2] = bfc(w0.z); bw[3] = bfc(w0.w);
                bw[4] = bfc(w1.x); bw[5] = bfc(w1.y); bw[6] = bfc(w1.z); bw[7] = bfc(w1.w);
                #pragma unroll
                for (int m = 0; m < 4; ++m)
                    oacc[m][n] = __builtin_amdgcn_mfma_f32_16x16x32_bf16(a[m], bw, oacc[m][n], 0, 0, 0);
            }
        }
        #pragma unroll
        for (int n = 0; n < 2; ++n) {
            const int j = wn * 32 + n * 16 + lr;
            const float bj = fc21b[j];
            #pragma unroll
            for (int m = 0; m < 4; ++m)
                #pragma unroll
                for (int r = 0; r < 4; ++r) {
                    const int row = wm * 64 + m * 16 + lg * 4 + r;
                    out[((size_t)b * DOUT + orow0 + row) * 64 + j] =
                        (oacc[m][n][r] + bj) * rowm[row];
                }
        }
    }
}

extern "C" void kernel_launch(void* const* d_in, const int* in_sizes, int n_in,
                              void* d_out, int out_size, void* d_ws, size_t ws_size,
                              hipStream_t stream) {
    const float* mu0   = (const float*)d_in[0];
    const float* lb1   = (const float*)d_in[1];
    const float* ub1   = (const float*)d_in[2];
    const float* lb2   = (const float*)d_in[3];
    const float* ub2   = (const float*)d_in[4];
    const float* ps1   = (const float*)d_in[5];
    const float* ss1   = (const float*)d_in[6];
    const float* ps2   = (const float*)d_in[7];
    const float* ss2   = (const float*)d_in[8];
    const float* mask1 = (const float*)d_in[9];
    const float* mask2 = (const float*)d_in[10];
    const float* W1    = (const float*)d_in[11];
    const float* b1    = (const float*)d_in[12];
    const float* W2    = (const float*)d_in[13];
    const float* b2    = (const float*)d_in[14];
    const float* fc1W  = (const float*)d_in[15];
    const float* fc1b  = (const float*)d_in[16];
    const float* fc11W = (const float*)d_in[17];
    const float* fc11b = (const float*)d_in[18];
    const float* fc2W  = (const float*)d_in[19];
    const float* fc2b  = (const float*)d_in[20];
    const float* fc21W = (const float*)d_in[21];
    const float* fc21b = (const float*)d_in[22];

    float* mu1 = (float*)d_out;
    float* mu2 = (float*)d_out + (size_t)16 * 4096 * 64;

    dim3 grid(16, 4096 / 128), blk(256);   // x = batch (16 blocks share a W panel)
    layer_kernel<2048><<<grid, blk, 0, stream>>>(
        W1, b1, mu0, lb1, ub1, ps1, ss1, mask1,
        fc1W, fc1b, fc11W, fc11b, fc2W, fc2b, fc21W, fc21b, mu1);
    layer_kernel<4096><<<grid, blk, 0, stream>>>(
        W2, b2, mu1, lb2, ub2, ps2, ss2, mask2,
        fc1W, fc1b, fc11W, fc11b, fc2W, fc2b, fc21W, fc21b, mu2);
}